// Round 2
// baseline (8825.987 us; speedup 1.0000x reference)
//
#include <hip/hip_runtime.h>
#include <math.h>

// Fixed topology
#define BB 64
#define TT 512
#define II 256
#define HH 512
#define OO 256
#define MM 256
#define BT (BB*TT)

// ---- workspace layout (float offsets) ----
// U1  : (B,T,H)  = x@W01^T + c1            (16,777,216 floats)
// U0  : (B,T,M)  = x@W0m^T + c3            ( 8,388,608)
// W1s : swizzled A1 (H*M = 131,072)
// W2s : swizzled [A2|A3 ; W12|Wm2] (1024 threads * 96 float4 = 393,216)
// c1, c2, c3
#define OFF_U1  0
#define OFF_U0  (OFF_U1 + BT*HH)
#define OFF_W1S (OFF_U0 + BT*MM)
#define OFF_W2S (OFF_W1S + HH*MM)
#define OFF_C1  (OFF_W2S + 393216)
#define OFF_C2  (OFF_C1 + HH)
#define OFF_C3  (OFF_C2 + OO)
#define WS_FLOATS (OFF_C3 + MM)
// total ~25.7M floats ~= 98 MB of ws

// swizzled index for phase-1 weights: element A1[h,k], k in [0,256)
__device__ __forceinline__ int w1s_index(int h, int k) {
    int p = h >> 1, r = h & 1;
    int ks = k >> 6, rem = k & 63;
    int j = rem >> 2, e = rem & 3;
    int tid = (p << 2) | ks;
    return OFF_W1S + ((j*2 + r)*1024 + tid)*4 + e;
}
// swizzled index for phase-2 weights: output row q (r=0 -> mem row, r=1 -> y row), k in [0,768)
__device__ __forceinline__ int w2s_index(int q, int r, int k) {
    int ks = k / 192, rem = k - ks*192;
    int j = rem >> 2, e = rem & 3;
    int tid = (q << 2) | ks;
    return OFF_W2S + ((j*2 + r)*1024 + tid)*4 + e;
}

// c1 = W01@bm0 + b01 + bm1 ; c2 = b12+bm2 ; c3 = W0m@bm0 + W2m@c2 + b0m+b1m+b2m
__global__ void pre_vecs(const float* __restrict__ W01, const float* __restrict__ b01,
                         const float* __restrict__ b12, const float* __restrict__ bm0,
                         const float* __restrict__ bm1, const float* __restrict__ bm2,
                         const float* __restrict__ W0m, const float* __restrict__ b0m,
                         const float* __restrict__ b1m, const float* __restrict__ b2m,
                         const float* __restrict__ W2m, float* __restrict__ ws) {
    int id = blockIdx.x*256 + threadIdx.x;  // grid 3*256 = 768
    if (id < HH) {
        float acc = b01[id] + bm1[id];
        for (int i = 0; i < II; ++i) acc += W01[id*II + i] * bm0[i];
        ws[OFF_C1 + id] = acc;
    } else if (id < HH + OO) {
        int m = id - HH;
        ws[OFF_C2 + m] = b12[m] + bm2[m];
        float acc = b0m[m] + b1m[m] + b2m[m];
        for (int i = 0; i < II; ++i) acc += W0m[m*II + i] * bm0[i];
        for (int o = 0; o < OO; ++o) acc += W2m[m*OO + o] * (b12[o] + bm2[o]);
        ws[OFF_C3 + m] = acc;
    }
}

// A1 = W01@Wm0 + Wm1, scattered into W1s. grid = H blocks (one h row), 256 threads (m)
__global__ void make_W1s(const float* __restrict__ W01, const float* __restrict__ Wm0,
                         const float* __restrict__ Wm1, float* __restrict__ ws) {
    int h = blockIdx.x, m = threadIdx.x;
    float acc = Wm1[h*MM + m];
    for (int i = 0; i < II; ++i) acc += W01[h*II + i] * Wm0[i*MM + m];
    ws[w1s_index(h, m)] = acc;
}

// A2 = W1m + W2m@W12 -> mem-row, k = h in [0,512). grid 256 (m) x 512 (h)
__global__ void make_A2(const float* __restrict__ W1m, const float* __restrict__ W2m,
                        const float* __restrict__ W12, float* __restrict__ ws) {
    int m = blockIdx.x, h = threadIdx.x;
    float acc = W1m[m*HH + h];
    for (int o = 0; o < OO; ++o) acc += W2m[m*OO + o] * W12[o*HH + h];
    ws[w2s_index(m, 0, h)] = acc;
}

// A3 = W0m@Wm0 + W2m@Wm2 -> mem-row, k = 512+m2. grid 256 (m) x 256 (m2)
__global__ void make_A3(const float* __restrict__ W0m, const float* __restrict__ Wm0,
                        const float* __restrict__ W2m, const float* __restrict__ Wm2,
                        float* __restrict__ ws) {
    int m = blockIdx.x, m2 = threadIdx.x;
    float acc = 0.f;
    for (int i = 0; i < II; ++i) acc += W0m[m*II + i] * Wm0[i*MM + m2];
    for (int o = 0; o < OO; ++o) acc += W2m[m*OO + o] * Wm2[o*MM + m2];
    ws[w2s_index(m, 0, 512 + m2)] = acc;
}

// y-row weights: [W12 row | Wm2 row]. grid 256 (q) x 768 (k)
__global__ void make_Wy(const float* __restrict__ W12, const float* __restrict__ Wm2,
                        float* __restrict__ ws) {
    int q = blockIdx.x, k = threadIdx.x;
    float v = (k < HH) ? W12[q*HH + k] : Wm2[q*MM + (k - HH)];
    ws[w2s_index(q, 1, k)] = v;
}

// out[n,c] = sum_k x[n,k]*W[c,k] + cvec[c]; K=256. 64x64 tile per block, 4x4 per thread,
// pure register tiling (L2-served broadcast loads; W tiles are L2-hot).
template<int N>
__global__ __launch_bounds__(256) void pre_gemm(const float* __restrict__ x, const float* __restrict__ W,
                                                const float* __restrict__ cvec, float* __restrict__ out) {
    const int tid = threadIdx.x;
    const int tx = tid & 15, ty = tid >> 4;
    const int n0 = blockIdx.x * 64 + 4*ty;
    const int c0 = blockIdx.y * 64 + 4*tx;
    const float4* x4 = reinterpret_cast<const float4*>(x) + (size_t)n0*64;
    const float4* W4 = reinterpret_cast<const float4*>(W) + (size_t)c0*64;
    float acc[4][4] = {};
    #pragma unroll 4
    for (int k4 = 0; k4 < 64; ++k4) {
        float4 a[4], w[4];
        #pragma unroll
        for (int r = 0; r < 4; ++r) a[r] = x4[r*64 + k4];
        #pragma unroll
        for (int c = 0; c < 4; ++c) w[c] = W4[c*64 + k4];
        #pragma unroll
        for (int r = 0; r < 4; ++r)
            #pragma unroll
            for (int c = 0; c < 4; ++c)
                acc[r][c] += a[r].x*w[c].x + a[r].y*w[c].y + a[r].z*w[c].z + a[r].w*w[c].w;
    }
    #pragma unroll
    for (int r = 0; r < 4; ++r) {
        float4 o;
        o.x = acc[r][0] + cvec[c0+0];
        o.y = acc[r][1] + cvec[c0+1];
        o.z = acc[r][2] + cvec[c0+2];
        o.w = acc[r][3] + cvec[c0+3];
        reinterpret_cast<float4*>(out)[(size_t)(n0 + r)*(N/4) + (c0>>2)] = o;
    }
}

// ---- main persistent recurrent kernel ----
// grid = 64 (one block per batch row), block = 1024 threads (16 waves).
// LDS act buffer, ping-pong: logical layout [v1(512) | mem(256)], physically
// pad-swizzled: addr(k) = k + 4*(k>>6)  (keeps the 4 per-wave broadcast
// addresses on disjoint banks; float4-alignment preserved).
__global__ __launch_bounds__(1024, 4) void rnn_main(const float* __restrict__ ws, float* __restrict__ out) {
    __shared__ float buf[2][816];
    const int tid = threadIdx.x;
    const int b = blockIdx.x;
    const int q = tid >> 2;        // 0..255
    const int ks = tid & 3;        // k-slice id
    const bool lead = (ks == 0);

    // init mem(t=0) = 0 in buf[0]
    if (tid < 256) { int k = 512 + tid; buf[0][k + ((k>>6)<<2)] = 0.f; }

    const float c2q = ws[OFF_C2 + q];
    const float4* W1s4 = reinterpret_cast<const float4*>(ws + OFF_W1S);
    const float4* W2s4 = reinterpret_cast<const float4*>(ws + OFF_W2S);
    const float* U1 = ws + OFF_U1 + (size_t)b*TT*HH;
    const float* U0 = ws + OFF_U0 + (size_t)b*TT*MM;
    __syncthreads();

    for (int t = 0; t < TT; ++t) {
        const int p = t & 1;
        const float4* bufp4 = reinterpret_cast<const float4*>(buf[p]);

        // ---- phase 1: v1 = act(U1[t] + mem @ A1^T) ----
        // thread computes k-slice [64*ks, 64*ks+64) for outputs h0=2q, h0+1
        float2 u1 = make_float2(0.f, 0.f);
        if (lead) u1 = *reinterpret_cast<const float2*>(U1 + t*HH + 2*q);
        float a0 = 0.f, a1 = 0.f;
        #pragma unroll 4
        for (int j = 0; j < 16; ++j) {
            float4 a  = bufp4[136 + 17*ks + j];          // mem[64ks+4j ..]
            float4 w0 = W1s4[(2*j)*1024 + tid];
            float4 w1 = W1s4[(2*j+1)*1024 + tid];
            a0 += w0.x*a.x + w0.y*a.y + w0.z*a.z + w0.w*a.w;
            a1 += w1.x*a.x + w1.y*a.y + w1.z*a.z + w1.w*a.w;
        }
        a0 += __shfl_xor(a0, 1); a0 += __shfl_xor(a0, 2);
        a1 += __shfl_xor(a1, 1); a1 += __shfl_xor(a1, 2);
        if (lead) {
            int h0 = 2*q;
            float v0 = a0 + u1.x, v1v = a1 + u1.y;
            if (h0 < 256) { v0 = fmaxf(v0, 0.f); v1v = fmaxf(v1v, 0.f); }  // wave-uniform
            else          { v0 = tanhf(v0);      v1v = tanhf(v1v);      }
            int ai = h0 + ((h0>>6)<<2);
            *reinterpret_cast<float2*>(&buf[p][ai]) = make_float2(v0, v1v);
        }
        __syncthreads();

        // ---- phase 2: mem' = U0[t] + [v1|mem]@[A2|A3]^T ;  y = [v1|mem]@[W12|Wm2]^T + c2 ----
        // thread computes k-slice [192*ks, 192*ks+192) for outputs mem'[q] and y[q]
        float u0 = 0.f;
        if (lead) u0 = U0[t*MM + q];
        float am = 0.f, ay = 0.f;
        #pragma unroll 4
        for (int j = 0; j < 48; ++j) {
            float4 a  = bufp4[51*ks + j + (j>>4)];       // act[192ks+4j ..]
            float4 w0 = W2s4[(2*j)*1024 + tid];
            float4 w1 = W2s4[(2*j+1)*1024 + tid];
            am += w0.x*a.x + w0.y*a.y + w0.z*a.z + w0.w*a.w;
            ay += w1.x*a.x + w1.y*a.y + w1.z*a.z + w1.w*a.w;
        }
        am += __shfl_xor(am, 1); am += __shfl_xor(am, 2);
        ay += __shfl_xor(ay, 1); ay += __shfl_xor(ay, 2);
        if (lead) {
            float mv = am + u0;
            int k = 512 + q;
            buf[p^1][k + ((k>>6)<<2)] = mv;
            out[((size_t)b*TT + t)*OO + q] = ay + c2q;
            if (t == TT-1) out[(size_t)BB*TT*OO + b*MM + q] = mv;
        }
        __syncthreads();
    }
}

extern "C" void kernel_launch(void* const* d_in, const int* in_sizes, int n_in,
                              void* d_out, int out_size, void* d_ws, size_t ws_size,
                              hipStream_t stream) {
    const float* inputs = (const float*)d_in[0];
    const float* W01 = (const float*)d_in[1];  const float* b01 = (const float*)d_in[2];
    const float* W12 = (const float*)d_in[3];  const float* b12 = (const float*)d_in[4];
    const float* Wm0 = (const float*)d_in[5];  const float* bm0 = (const float*)d_in[6];
    const float* Wm1 = (const float*)d_in[7];  const float* bm1 = (const float*)d_in[8];
    const float* Wm2 = (const float*)d_in[9];  const float* bm2 = (const float*)d_in[10];
    const float* W0m = (const float*)d_in[11]; const float* b0m = (const float*)d_in[12];
    const float* W1m = (const float*)d_in[13]; const float* b1m = (const float*)d_in[14];
    const float* W2m = (const float*)d_in[15]; const float* b2m = (const float*)d_in[16];
    float* outf = (float*)d_out;
    float* wsf = (float*)d_ws;

    // Guard: if the harness workspace is smaller than our layout, do NOT write
    // OOB (that can fault the GPU and kill the container). Returning here makes
    // the run report "incorrect" instead — a diagnosable signal.
    if (ws_size < (size_t)WS_FLOATS * sizeof(float)) return;

    // fused-weight / bias precompute
    pre_vecs<<<3, 256, 0, stream>>>(W01, b01, b12, bm0, bm1, bm2, W0m, b0m, b1m, b2m, W2m, wsf);
    make_W1s<<<HH, 256, 0, stream>>>(W01, Wm0, Wm1, wsf);
    make_A2<<<MM, 512, 0, stream>>>(W1m, W2m, W12, wsf);
    make_A3<<<MM, 256, 0, stream>>>(W0m, Wm0, W2m, Wm2, wsf);
    make_Wy<<<OO, 768, 0, stream>>>(W12, Wm2, wsf);
    // input-projection precompute (parallel over all b,t)
    pre_gemm<HH><<<dim3(BT/64, HH/64), 256, 0, stream>>>(inputs, W01, wsf + OFF_C1, wsf + OFF_U1);
    pre_gemm<MM><<<dim3(BT/64, MM/64), 256, 0, stream>>>(inputs, W0m, wsf + OFF_C3, wsf + OFF_U0);
    // recurrent sweep: one persistent block per batch row
    rnn_main<<<BB, 1024, 0, stream>>>(wsf, outf);
}